// Round 2
// baseline (403.206 us; speedup 1.0000x reference)
//
#include <hip/hip_runtime.h>
#include <hip/hip_bf16.h>
#include <stdint.h>

#define OUT_N 4096
#define IN_N  4096
#define BATCH 2048
#define KHALF 2049   // IN/2 + 1

typedef __bf16 bf16x8 __attribute__((ext_vector_type(8)));
typedef float  f32x4  __attribute__((ext_vector_type(4)));

__device__ __forceinline__ unsigned short f2bf(float f) {
  unsigned int u = __builtin_bit_cast(unsigned int, f);
  u += 0x7FFFu + ((u >> 16) & 1u);   // round-to-nearest-even
  return (unsigned short)(u >> 16);
}

// ---------------------------------------------------------------------------
// complex helpers
// ---------------------------------------------------------------------------
__device__ __forceinline__ float2 cmul(float2 a, float2 b) {
  return make_float2(a.x * b.x - a.y * b.y, a.x * b.y + a.y * b.x);
}
__device__ __forceinline__ float2 cadd(float2 a, float2 b) { return make_float2(a.x + b.x, a.y + b.y); }
__device__ __forceinline__ float2 csub(float2 a, float2 b) { return make_float2(a.x - b.x, a.y - b.y); }
__device__ __forceinline__ float2 muli(float2 a) { return make_float2(-a.y, a.x); }  // *e^{+i pi/2}

// inverse DFT4 (w = +i)
__device__ __forceinline__ void dft4i(float2& x0, float2& x1, float2& x2, float2& x3) {
  float2 t0 = cadd(x0, x2), t1 = csub(x0, x2);
  float2 t2 = cadd(x1, x3), t3 = csub(x1, x3);
  float2 it3 = muli(t3);
  x0 = cadd(t0, t2); x2 = csub(t0, t2);
  x1 = cadd(t1, it3); x3 = csub(t1, it3);
}

#define C8f  0.70710678118654752f
#define C16f 0.92387953251128676f
#define S16f 0.38268343236508977f

// inverse DFT16 in registers
__device__ __forceinline__ void dft16i(float2 r[16]) {
  float2 t[16];
#pragma unroll
  for (int b = 0; b < 4; ++b) {
    float2 a0 = r[b], a1 = r[4 + b], a2 = r[8 + b], a3 = r[12 + b];
    dft4i(a0, a1, a2, a3);
    t[b * 4 + 0] = a0; t[b * 4 + 1] = a1; t[b * 4 + 2] = a2; t[b * 4 + 3] = a3;
  }
  const float2 W1 = make_float2(C16f, S16f);
  const float2 W2 = make_float2(C8f, C8f);
  const float2 W3 = make_float2(S16f, C16f);
  const float2 W6 = make_float2(-C8f, C8f);
  const float2 W9 = make_float2(-C16f, -S16f);
  t[5]  = cmul(t[5],  W1);  t[6]  = cmul(t[6],  W2);  t[7]  = cmul(t[7],  W3);
  t[9]  = cmul(t[9],  W2);  t[10] = muli(t[10]);      t[11] = cmul(t[11], W6);
  t[13] = cmul(t[13], W3);  t[14] = cmul(t[14], W6);  t[15] = cmul(t[15], W9);
#pragma unroll
  for (int q = 0; q < 4; ++q) {
    float2 a0 = t[q], a1 = t[4 + q], a2 = t[8 + q], a3 = t[12 + q];
    dft4i(a0, a1, a2, a3);
    r[q] = a0; r[q + 4] = a1; r[q + 8] = a2; r[q + 12] = a3;
  }
}

// apply r[k] *= e^{i k theta} for k=1..15 via recurrence
__device__ __forceinline__ void twiddle16(float2 r[16], float theta) {
  float sn, cs;
  __sincosf(theta, &sn, &cs);
  float2 w = make_float2(cs, sn);
  float2 wk = w;
  r[1] = cmul(r[1], wk);
#pragma unroll
  for (int k = 2; k < 16; ++k) {
    wk = cmul(wk, w);
    r[k] = cmul(r[k], wk);
  }
}

// ---------------------------------------------------------------------------
// 4096-pt inverse FFT (unnormalized, e^{+i}), radix 16^3 in registers.
// Entry: thread t holds r[n1] = x[256*n1 + t].  Exit: r[d] = X[t + 256*d].
// LDS workspace: EXACTLY 4096 float2 (32 KB) -> 5 blocks/CU (was 4368/34.9KB
// with pitch-257/273 padding -> 4 blocks/CU).  Bank spread comes from a
// per-row XOR swizzle: slot (row k1, col j) -> k1*256 + (j ^ k1); bijective
// per row, and every access phase lands exactly 4 lanes per bank-pair
// (= the wave64-b64 floor, same distribution as the old padded scheme).
// Caller must sync before calling if lds fed r.
// ---------------------------------------------------------------------------
__device__ void fft4096_core(float2 r[16], float2* lds, int t) {
  dft16i(r);
  twiddle16(r, 1.53398078788564123e-3f * (float)t);   // 2*pi/4096 * t
#pragma unroll
  for (int k1 = 0; k1 < 16; ++k1) lds[k1 * 256 + (t ^ k1)] = r[k1];
  __syncthreads();
  const int k1 = t & 15, b = t >> 4;
  float2 s[16];
#pragma unroll
  for (int a = 0; a < 16; ++a) s[a] = lds[k1 * 256 + ((16 * a + b) ^ k1)];
  __syncthreads();
  dft16i(s);
  twiddle16(s, 2.45436926061702596e-2f * (float)b);   // 2*pi/256 * b
#pragma unroll
  for (int c = 0; c < 16; ++c) lds[k1 * 256 + ((c * 16 + b) ^ k1)] = s[c];
  __syncthreads();
#pragma unroll
  for (int bb = 0; bb < 16; ++bb) r[bb] = lds[k1 * 256 + ((b * 16 + bb) ^ k1)];
  dft16i(r);
}

// ---------------------------------------------------------------------------
// P1: mask + transpose. W[o][k] (k<2049) -> WT[k][o] (complex float2)
// 64(k) x 32(o) tiles, float2/int2 loads. blockIdx.x==32 handles k=2048.
// ---------------------------------------------------------------------------
__global__ void mask_transpose(const float* __restrict__ wr, const float* __restrict__ wi,
                               const int* __restrict__ zmat, float2* __restrict__ wt) {
  __shared__ float2 tile[32][65];   // [o-local][k-local], pitch 65 -> 2-way (free)
  const int tx = threadIdx.x;       // 0..31
  const int ty = threadIdx.y;       // 0..7
  const int o0 = blockIdx.y * 32;
  if (blockIdx.x == 32) {           // Nyquist column k = 2048
    int t = ty * 32 + tx;
    if (t < 32) {
      int o = o0 + t;
      size_t idx = (size_t)o * IN_N + 2048;
      float2 v = make_float2(0.f, 0.f);
      if (zmat[idx] <= 8388608) v = make_float2(wr[idx], wi[idx]);
      wt[(size_t)2048 * OUT_N + o] = v;
    }
    return;
  }
  const int k0 = blockIdx.x * 64;
#pragma unroll
  for (int r = 0; r < 4; ++r) {
    int o = o0 + ty + r * 8;
    size_t base = (size_t)o * IN_N + k0 + tx * 2;
    float2 vr = *(const float2*)&wr[base];
    float2 vi = *(const float2*)&wi[base];
    int2   z  = *(const int2*)&zmat[base];
    tile[ty + r * 8][tx * 2]     = (z.x <= 8388608) ? make_float2(vr.x, vi.x) : make_float2(0.f, 0.f);
    tile[ty + r * 8][tx * 2 + 1] = (z.y <= 8388608) ? make_float2(vr.y, vi.y) : make_float2(0.f, 0.f);
  }
  __syncthreads();
#pragma unroll
  for (int rr = 0; rr < 8; ++rr) {
    int k = k0 + ty + rr * 8;
    int o = o0 + tx;
    wt[(size_t)k * OUT_N + o] = tile[tx][ty + rr * 8];
  }
}

// ---------------------------------------------------------------------------
// P2: per-row inverse FFT of WT, in place, UNnormalized (1/4096^2 in P4)
// LDS = 32 KB exactly; min-waves 5 asks the allocator to stay <=102 VGPR so
// the 5th block/CU actually materializes.
// ---------------------------------------------------------------------------
__global__ __launch_bounds__(256, 5) void col_ifft(float2* __restrict__ wt) {
  __shared__ float2 lds[4096];
  const int t = threadIdx.x;
  float2* row = wt + (size_t)blockIdx.x * OUT_N;
  float2 r[16];
#pragma unroll
  for (int n1 = 0; n1 < 16; ++n1) r[n1] = row[n1 * 256 + t];
  fft4096_core(r, lds, t);
#pragma unroll
  for (int d = 0; d < 16; ++d) row[t + 256 * d] = r[d];
}

// ---------------------------------------------------------------------------
// P3: transpose YT[k][o] (2049 x 4096) -> Y[o][k] (4096 x 2049)
// ---------------------------------------------------------------------------
__global__ void transpose_ko(const float2* __restrict__ yt, float2* __restrict__ y) {
  __shared__ float2 tile[32][33];
  const int k0 = blockIdx.x * 32;
  const int o0 = blockIdx.y * 32;
  const int tx = threadIdx.x;
  const int ty = threadIdx.y;
#pragma unroll
  for (int r = 0; r < 4; ++r) {
    int k = k0 + ty + r * 8;
    int o = o0 + tx;
    if (k < KHALF) tile[ty + r * 8][tx] = yt[(size_t)k * OUT_N + o];
  }
  __syncthreads();
#pragma unroll
  for (int r = 0; r < 4; ++r) {
    int o = o0 + ty + r * 8;
    int k = k0 + tx;
    if (k < KHALF) y[(size_t)o * KHALF + k] = tile[tx][ty + r * 8];
  }
}

// ---------------------------------------------------------------------------
// P4: TWO rows per block: ifft(Ya_ext + i*Yb_ext) = a + i*b exactly.
// Scale = 1/(4096*4096) (covers P2's skipped normalization too).
// LDS staging holds k=0..2047 only (2048+2048 = 4096 float2 = 32 KB); the
// single Nyquist element k=2048 is read straight from global by the one lane
// (n1==8, t==0) that needs it.
// ---------------------------------------------------------------------------
__global__ __launch_bounds__(256, 5) void row_irfft2(const float2* __restrict__ y,
                                                     unsigned short* __restrict__ wbf) {
  __shared__ float2 lds[4096];
  const int t = threadIdx.x;
  const int oa = blockIdx.x * 2, ob = oa + 1;
  const float2* rowa = y + (size_t)oa * KHALF;
  const float2* rowb = y + (size_t)ob * KHALF;
  float2* lsa = lds;          // [0, 2048)
  float2* lsb = lds + 2048;   // [2048, 4096)
#pragma unroll
  for (int j = 0; j < 8; ++j) {
    int k = t + j * 256;      // 0..2047, no guard needed
    lsa[k] = rowa[k]; lsb[k] = rowb[k];
  }
  __syncthreads();
  float2 r[16];
#pragma unroll
  for (int n1 = 0; n1 < 16; ++n1) {
    int m = n1 * 256 + t;
    float2 za, zb;
    if (m == 0)        { za = make_float2(lsa[0].x, 0.f);    zb = make_float2(lsb[0].x, 0.f); }
    else if (m < 2048) { za = lsa[m];                        zb = lsb[m]; }
    else if (m == 2048){ float2 na = rowa[2048], nb = rowb[2048];   // single-lane global read
                         za = make_float2(na.x, 0.f);        zb = make_float2(nb.x, 0.f); }
    else { float2 ua = lsa[4096 - m], ub = lsb[4096 - m];
           za = make_float2(ua.x, -ua.y); zb = make_float2(ub.x, -ub.y); }
    r[n1] = make_float2(za.x - zb.y, za.y + zb.x);   // za + i*zb
  }
  __syncthreads();
  fft4096_core(r, lds, t);
  const float sc = 1.0f / (4096.0f * 4096.0f);
  unsigned short* orow_a = wbf + (size_t)oa * IN_N;
  unsigned short* orow_b = wbf + (size_t)ob * IN_N;
#pragma unroll
  for (int d = 0; d < 16; ++d) {
    orow_a[t + 256 * d] = f2bf(r[d].x * sc);
    orow_b[t + 256 * d] = f2bf(r[d].y * sc);
  }
}

// ---------------------------------------------------------------------------
// P5: data f32 -> bf16
// ---------------------------------------------------------------------------
__global__ void cvt_bf16(const float* __restrict__ x, unsigned short* __restrict__ o, int n4) {
  int i = blockIdx.x * blockDim.x + threadIdx.x;
  if (i < n4) {
    float4 v = ((const float4*)x)[i];
    ushort4 r;
    r.x = f2bf(v.x); r.y = f2bf(v.y); r.z = f2bf(v.z); r.w = f2bf(v.w);
    ((ushort4*)o)[i] = r;
  }
}

// ---------------------------------------------------------------------------
// P6: C[M,N] = A[M,K] * B[N,K]^T + bias  (bf16 in, f32 out)
// 256 thr / 4 waves (2x2 of 64x64), 128x128 tile, BK=64, XOR-swizzled LDS.
// Explicit 2-slot double-buffer with COUNTED vmcnt (T3/T4 minimum):
//   prologue stages tiles 0,1; each iter waits vmcnt(8) (tile t landed, tile
//   t+1's 8 loads stay IN FLIGHT across both barriers), computes slot t&1,
//   then stages tile t+2 into the slot just freed.  Grid gives only 2
//   blocks/CU (512 WGs) so cross-barrier prefetch substitutes for TLP that
//   m97-structure kernels get from 4 blocks/CU.
// sched_barrier(0) after each waitcnt pins code motion (methodology rule #18).
// Swizzle: LDS[row][chunk c] holds global 16B-chunk (c ^ (row&7)); staging
// stays contiguous in lane order (global_load_lds requirement) while
// fragment ds_read_b128 spreads 16 rows over all 32 banks (2-way = free).
// ---------------------------------------------------------------------------
#define BK 64
#define NT (IN_N / BK)

__device__ __forceinline__ void gload_lds16(const void* gp, void* lp) {
  typedef const __attribute__((address_space(1))) void* gptr_t;
  typedef __attribute__((address_space(3))) void* lptr_t;
  __builtin_amdgcn_global_load_lds((gptr_t)(unsigned long long)gp,
                                   (lptr_t)(unsigned int)(unsigned long long)lp,
                                   16, 0, 0);
}

// stage one 128x64 A-tile + B-tile into slot LDS (8 gloads/thread = 8 vmcnt
// ticks/wave; all waves issue uniformly so vmcnt bookkeeping is wave-uniform)
__device__ __forceinline__ void stage_tile(const unsigned short* __restrict__ A,
                                           const unsigned short* __restrict__ B,
                                           unsigned short* as, unsigned short* bs,
                                           int gm0, int gn0, int kt,
                                           int r0, int srow, int schunk) {
#pragma unroll
  for (int j = 0; j < 4; ++j) {
    gload_lds16(A + ((size_t)(gm0 + r0 + j * 8 + srow) * IN_N + kt + schunk * 8),
                as + (size_t)(r0 + j * 8) * BK);
    gload_lds16(B + ((size_t)(gn0 + r0 + j * 8 + srow) * IN_N + kt + schunk * 8),
                bs + (size_t)(r0 + j * 8) * BK);
  }
}

__global__ __launch_bounds__(256) void gemm_bt_bias(const unsigned short* __restrict__ A,
                                                    const unsigned short* __restrict__ B,
                                                    const float* __restrict__ bias,
                                                    float* __restrict__ C) {
  __shared__ __align__(16) unsigned short As[2][128 * BK];   // 2 x 16 KB
  __shared__ __align__(16) unsigned short Bs[2][128 * BK];   // 2 x 16 KB
  const int tid  = threadIdx.x;
  const int wave = tid >> 6;
  const int lane = tid & 63;
  const int gm0 = blockIdx.y * 128;
  const int gn0 = blockIdx.x * 128;

  f32x4 acc[4][4] = {};
  const int wm = wave >> 1, wn = wave & 1;     // 2x2 waves, 64x64 each
  // staging map: dest row r0+ (lane>>3), dest chunk lane&7 gets src chunk ^row
  const int srow   = lane >> 3;                // 0..7
  const int schunk = (lane & 7) ^ srow;        // XOR swizzle
  const int r0     = wave * 32;                // per-wave staging row base
  // fragment map
  const int l7 = lane & 7;
  const int qbase = lane >> 4;                 // 0..3
  const int fra = wm * 64 + (lane & 15);
  const int frb = wn * 64 + (lane & 15);

  // prologue: fill both slots
  stage_tile(A, B, As[0], Bs[0], gm0, gn0, 0,  r0, srow, schunk);
  stage_tile(A, B, As[1], Bs[1], gm0, gn0, BK, r0, srow, schunk);

  for (int t = 0; t < NT; ++t) {
    const int S = t & 1;
    // tile t landed (everything except the newest 8 loads = tile t+1);
    // last iter has nothing in flight behind it -> drain.
    if (t < NT - 1) asm volatile("s_waitcnt vmcnt(8)" ::: "memory");
    else            asm volatile("s_waitcnt vmcnt(0)" ::: "memory");
    __builtin_amdgcn_sched_barrier(0);   // rule #18: pin code motion at the wait
    __builtin_amdgcn_s_barrier();        // raw barrier: no implicit vmcnt(0) drain
    __builtin_amdgcn_sched_barrier(0);

#pragma unroll
    for (int kk = 0; kk < 2; ++kk) {
      bf16x8 af[4], bfr[4];
      const int q = kk * 4 + qbase;            // logical 16B chunk 0..7
#pragma unroll
      for (int i = 0; i < 4; ++i) {
        af[i]  = *(const bf16x8*)&As[S][(fra + i * 16) * BK + ((q ^ l7) * 8)];
        bfr[i] = *(const bf16x8*)&Bs[S][(frb + i * 16) * BK + ((q ^ l7) * 8)];
      }
#pragma unroll
      for (int mi = 0; mi < 4; ++mi)
#pragma unroll
        for (int ni = 0; ni < 4; ++ni)
          acc[mi][ni] = __builtin_amdgcn_mfma_f32_16x16x32_bf16(af[mi], bfr[ni], acc[mi][ni], 0, 0, 0);
    }
    __builtin_amdgcn_sched_barrier(0);
    __builtin_amdgcn_s_barrier();   // all waves done reading slot S
    if (t + 2 < NT)                 // refill the slot just freed
      stage_tile(A, B, As[S], Bs[S], gm0, gn0, (t + 2) * BK, r0, srow, schunk);
  }

  // epilogue: C/D layout col = lane&15, row = (lane>>4)*4 + r   [m89/m91]
  const int col0 = gn0 + wn * 64 + (lane & 15);
  const int row0 = gm0 + wm * 64 + (lane >> 4) * 4;
#pragma unroll
  for (int mi = 0; mi < 4; ++mi) {
#pragma unroll
    for (int ni = 0; ni < 4; ++ni) {
      int col = col0 + ni * 16;
      float bv = bias[col];
#pragma unroll
      for (int r = 0; r < 4; ++r) {
        int row = row0 + mi * 16 + r;
        C[(size_t)row * OUT_N + col] = acc[mi][ni][r] + bv;
      }
    }
  }
}

// ---------------------------------------------------------------------------
extern "C" void kernel_launch(void* const* d_in, const int* in_sizes, int n_in,
                              void* d_out, int out_size, void* d_ws, size_t ws_size,
                              hipStream_t stream) {
  const float* data = (const float*)d_in[0];
  const float* wr   = (const float*)d_in[1];
  const float* wi   = (const float*)d_in[2];
  const float* bias = (const float*)d_in[3];
  const int*   zmat = (const int*)d_in[4];

  char* ws = (char*)d_ws;
  float2* wt = (float2*)ws;                                  // 2049*4096*8
  float2* y  = (float2*)(ws + 67141632ull);                  // 4096*2049*8
  unsigned short* wbf = (unsigned short*)ws;                 // 4096*4096*2 (over dead wt)
  unsigned short* dbf = (unsigned short*)(ws + 33554432ull); // 2048*4096*2

  hipLaunchKernelGGL(mask_transpose, dim3(33, 128), dim3(32, 8), 0, stream, wr, wi, zmat, wt);
  hipLaunchKernelGGL(col_ifft,       dim3(2049),    dim3(256),   0, stream, wt);
  hipLaunchKernelGGL(transpose_ko,   dim3(65, 128), dim3(32, 8), 0, stream, wt, y);
  hipLaunchKernelGGL(row_irfft2,     dim3(2048),    dim3(256),   0, stream, y, wbf);
  hipLaunchKernelGGL(cvt_bf16,       dim3(8192),    dim3(256),   0, stream, data, dbf, (BATCH * IN_N) / 4);
  hipLaunchKernelGGL(gemm_bt_bias,   dim3(OUT_N / 128, BATCH / 128), dim3(256), 0, stream,
                     dbf, wbf, bias, (float*)d_out);
}

// Round 3
// 354.507 us; speedup vs baseline: 1.1374x; 1.1374x over previous
//
#include <hip/hip_runtime.h>
#include <hip/hip_bf16.h>
#include <stdint.h>

#define OUT_N 4096
#define IN_N  4096
#define BATCH 2048
#define KHALF 2049   // IN/2 + 1

typedef __bf16 bf16x8 __attribute__((ext_vector_type(8)));
typedef float  f32x4  __attribute__((ext_vector_type(4)));

__device__ __forceinline__ unsigned short f2bf(float f) {
  unsigned int u = __builtin_bit_cast(unsigned int, f);
  u += 0x7FFFu + ((u >> 16) & 1u);   // round-to-nearest-even
  return (unsigned short)(u >> 16);
}

// ---------------------------------------------------------------------------
// complex helpers
// ---------------------------------------------------------------------------
__device__ __forceinline__ float2 cmul(float2 a, float2 b) {
  return make_float2(a.x * b.x - a.y * b.y, a.x * b.y + a.y * b.x);
}
__device__ __forceinline__ float2 cadd(float2 a, float2 b) { return make_float2(a.x + b.x, a.y + b.y); }
__device__ __forceinline__ float2 csub(float2 a, float2 b) { return make_float2(a.x - b.x, a.y - b.y); }
__device__ __forceinline__ float2 muli(float2 a) { return make_float2(-a.y, a.x); }  // *e^{+i pi/2}

// inverse DFT4 (w = +i)
__device__ __forceinline__ void dft4i(float2& x0, float2& x1, float2& x2, float2& x3) {
  float2 t0 = cadd(x0, x2), t1 = csub(x0, x2);
  float2 t2 = cadd(x1, x3), t3 = csub(x1, x3);
  float2 it3 = muli(t3);
  x0 = cadd(t0, t2); x2 = csub(t0, t2);
  x1 = cadd(t1, it3); x3 = csub(t1, it3);
}

#define C8f  0.70710678118654752f
#define C16f 0.92387953251128676f
#define S16f 0.38268343236508977f

// inverse DFT16 in registers
__device__ __forceinline__ void dft16i(float2 r[16]) {
  float2 t[16];
#pragma unroll
  for (int b = 0; b < 4; ++b) {
    float2 a0 = r[b], a1 = r[4 + b], a2 = r[8 + b], a3 = r[12 + b];
    dft4i(a0, a1, a2, a3);
    t[b * 4 + 0] = a0; t[b * 4 + 1] = a1; t[b * 4 + 2] = a2; t[b * 4 + 3] = a3;
  }
  const float2 W1 = make_float2(C16f, S16f);
  const float2 W2 = make_float2(C8f, C8f);
  const float2 W3 = make_float2(S16f, C16f);
  const float2 W6 = make_float2(-C8f, C8f);
  const float2 W9 = make_float2(-C16f, -S16f);
  t[5]  = cmul(t[5],  W1);  t[6]  = cmul(t[6],  W2);  t[7]  = cmul(t[7],  W3);
  t[9]  = cmul(t[9],  W2);  t[10] = muli(t[10]);      t[11] = cmul(t[11], W6);
  t[13] = cmul(t[13], W3);  t[14] = cmul(t[14], W6);  t[15] = cmul(t[15], W9);
#pragma unroll
  for (int q = 0; q < 4; ++q) {
    float2 a0 = t[q], a1 = t[4 + q], a2 = t[8 + q], a3 = t[12 + q];
    dft4i(a0, a1, a2, a3);
    r[q] = a0; r[q + 4] = a1; r[q + 8] = a2; r[q + 12] = a3;
  }
}

// apply r[k] *= e^{i k theta} for k=1..15 via recurrence
__device__ __forceinline__ void twiddle16(float2 r[16], float theta) {
  float sn, cs;
  __sincosf(theta, &sn, &cs);
  float2 w = make_float2(cs, sn);
  float2 wk = w;
  r[1] = cmul(r[1], wk);
#pragma unroll
  for (int k = 2; k < 16; ++k) {
    wk = cmul(wk, w);
    r[k] = cmul(r[k], wk);
  }
}

// ---------------------------------------------------------------------------
// 4096-pt inverse FFT (unnormalized, e^{+i}), radix 16^3 in registers.
// Entry: thread t holds r[n1] = x[256*n1 + t].  Exit: r[d] = X[t + 256*d].
// LDS workspace: EXACTLY 4096 float2 (32 KB).  Bank spread via per-row XOR
// swizzle: slot (row k1, col j) -> k1*256 + (j ^ k1); bijective per row, and
// every access phase lands exactly 4 lanes per bank-pair (= wave64-b64
// floor, same distribution as a padded pitch-257/273 scheme).
// Caller must sync before calling if lds fed r.
// ---------------------------------------------------------------------------
__device__ void fft4096_core(float2 r[16], float2* lds, int t) {
  dft16i(r);
  twiddle16(r, 1.53398078788564123e-3f * (float)t);   // 2*pi/4096 * t
#pragma unroll
  for (int k1 = 0; k1 < 16; ++k1) lds[k1 * 256 + (t ^ k1)] = r[k1];
  __syncthreads();
  const int k1 = t & 15, b = t >> 4;
  float2 s[16];
#pragma unroll
  for (int a = 0; a < 16; ++a) s[a] = lds[k1 * 256 + ((16 * a + b) ^ k1)];
  __syncthreads();
  dft16i(s);
  twiddle16(s, 2.45436926061702596e-2f * (float)b);   // 2*pi/256 * b
#pragma unroll
  for (int c = 0; c < 16; ++c) lds[k1 * 256 + ((c * 16 + b) ^ k1)] = s[c];
  __syncthreads();
#pragma unroll
  for (int bb = 0; bb < 16; ++bb) r[bb] = lds[k1 * 256 + ((b * 16 + bb) ^ k1)];
  dft16i(r);
}

// ---------------------------------------------------------------------------
// P1: mask + transpose. W[o][k] (k<2049) -> WT[k][o] (complex float2)
// 64(k) x 32(o) tiles, float2/int2 loads. blockIdx.x==32 handles k=2048.
// ---------------------------------------------------------------------------
__global__ void mask_transpose(const float* __restrict__ wr, const float* __restrict__ wi,
                               const int* __restrict__ zmat, float2* __restrict__ wt) {
  __shared__ float2 tile[32][65];   // [o-local][k-local], pitch 65 -> 2-way (free)
  const int tx = threadIdx.x;       // 0..31
  const int ty = threadIdx.y;       // 0..7
  const int o0 = blockIdx.y * 32;
  if (blockIdx.x == 32) {           // Nyquist column k = 2048
    int t = ty * 32 + tx;
    if (t < 32) {
      int o = o0 + t;
      size_t idx = (size_t)o * IN_N + 2048;
      float2 v = make_float2(0.f, 0.f);
      if (zmat[idx] <= 8388608) v = make_float2(wr[idx], wi[idx]);
      wt[(size_t)2048 * OUT_N + o] = v;
    }
    return;
  }
  const int k0 = blockIdx.x * 64;
#pragma unroll
  for (int r = 0; r < 4; ++r) {
    int o = o0 + ty + r * 8;
    size_t base = (size_t)o * IN_N + k0 + tx * 2;
    float2 vr = *(const float2*)&wr[base];
    float2 vi = *(const float2*)&wi[base];
    int2   z  = *(const int2*)&zmat[base];
    tile[ty + r * 8][tx * 2]     = (z.x <= 8388608) ? make_float2(vr.x, vi.x) : make_float2(0.f, 0.f);
    tile[ty + r * 8][tx * 2 + 1] = (z.y <= 8388608) ? make_float2(vr.y, vi.y) : make_float2(0.f, 0.f);
  }
  __syncthreads();
#pragma unroll
  for (int rr = 0; rr < 8; ++rr) {
    int k = k0 + ty + rr * 8;
    int o = o0 + tx;
    wt[(size_t)k * OUT_N + o] = tile[tx][ty + rr * 8];
  }
}

// ---------------------------------------------------------------------------
// P2: per-row inverse FFT of WT, in place, UNnormalized (1/4096^2 in P4)
// NOTE: no min-waves clause — R2's __launch_bounds__(256,5) capped the
// allocator at ~102 VGPR and regressed ~50 us (spill suspect). Let the
// allocator pick; LDS is 32 KB so occupancy is register-bound as HW decides.
// ---------------------------------------------------------------------------
__global__ __launch_bounds__(256) void col_ifft(float2* __restrict__ wt) {
  __shared__ float2 lds[4096];
  const int t = threadIdx.x;
  float2* row = wt + (size_t)blockIdx.x * OUT_N;
  float2 r[16];
#pragma unroll
  for (int n1 = 0; n1 < 16; ++n1) r[n1] = row[n1 * 256 + t];
  fft4096_core(r, lds, t);
#pragma unroll
  for (int d = 0; d < 16; ++d) row[t + 256 * d] = r[d];
}

// ---------------------------------------------------------------------------
// P3: transpose YT[k][o] (2049 x 4096) -> Y[o][k] (4096 x 2049)
// ---------------------------------------------------------------------------
__global__ void transpose_ko(const float2* __restrict__ yt, float2* __restrict__ y) {
  __shared__ float2 tile[32][33];
  const int k0 = blockIdx.x * 32;
  const int o0 = blockIdx.y * 32;
  const int tx = threadIdx.x;
  const int ty = threadIdx.y;
#pragma unroll
  for (int r = 0; r < 4; ++r) {
    int k = k0 + ty + r * 8;
    int o = o0 + tx;
    if (k < KHALF) tile[ty + r * 8][tx] = yt[(size_t)k * OUT_N + o];
  }
  __syncthreads();
#pragma unroll
  for (int r = 0; r < 4; ++r) {
    int o = o0 + ty + r * 8;
    int k = k0 + tx;
    if (k < KHALF) y[(size_t)o * KHALF + k] = tile[tx][ty + r * 8];
  }
}

// ---------------------------------------------------------------------------
// P4: TWO rows per block: ifft(Ya_ext + i*Yb_ext) = a + i*b exactly.
// Scale = 1/(4096*4096) (covers P2's skipped normalization too).
// LDS staging holds k=0..2047 only (2048+2048 = 4096 float2 = 32 KB); the
// single Nyquist element k=2048 is read straight from global by the one lane
// (n1==8, t==0) that needs it.  No min-waves clause (see P2 note).
// ---------------------------------------------------------------------------
__global__ __launch_bounds__(256) void row_irfft2(const float2* __restrict__ y,
                                                  unsigned short* __restrict__ wbf) {
  __shared__ float2 lds[4096];
  const int t = threadIdx.x;
  const int oa = blockIdx.x * 2, ob = oa + 1;
  const float2* rowa = y + (size_t)oa * KHALF;
  const float2* rowb = y + (size_t)ob * KHALF;
  float2* lsa = lds;          // [0, 2048)
  float2* lsb = lds + 2048;   // [2048, 4096)
#pragma unroll
  for (int j = 0; j < 8; ++j) {
    int k = t + j * 256;      // 0..2047, no guard needed
    lsa[k] = rowa[k]; lsb[k] = rowb[k];
  }
  __syncthreads();
  float2 r[16];
#pragma unroll
  for (int n1 = 0; n1 < 16; ++n1) {
    int m = n1 * 256 + t;
    float2 za, zb;
    if (m == 0)        { za = make_float2(lsa[0].x, 0.f);    zb = make_float2(lsb[0].x, 0.f); }
    else if (m < 2048) { za = lsa[m];                        zb = lsb[m]; }
    else if (m == 2048){ float2 na = rowa[2048], nb = rowb[2048];   // single-lane global read
                         za = make_float2(na.x, 0.f);        zb = make_float2(nb.x, 0.f); }
    else { float2 ua = lsa[4096 - m], ub = lsb[4096 - m];
           za = make_float2(ua.x, -ua.y); zb = make_float2(ub.x, -ub.y); }
    r[n1] = make_float2(za.x - zb.y, za.y + zb.x);   // za + i*zb
  }
  __syncthreads();
  fft4096_core(r, lds, t);
  const float sc = 1.0f / (4096.0f * 4096.0f);
  unsigned short* orow_a = wbf + (size_t)oa * IN_N;
  unsigned short* orow_b = wbf + (size_t)ob * IN_N;
#pragma unroll
  for (int d = 0; d < 16; ++d) {
    orow_a[t + 256 * d] = f2bf(r[d].x * sc);
    orow_b[t + 256 * d] = f2bf(r[d].y * sc);
  }
}

// ---------------------------------------------------------------------------
// P5: data f32 -> bf16
// ---------------------------------------------------------------------------
__global__ void cvt_bf16(const float* __restrict__ x, unsigned short* __restrict__ o, int n4) {
  int i = blockIdx.x * blockDim.x + threadIdx.x;
  if (i < n4) {
    float4 v = ((const float4*)x)[i];
    ushort4 r;
    r.x = f2bf(v.x); r.y = f2bf(v.y); r.z = f2bf(v.z); r.w = f2bf(v.w);
    ((ushort4*)o)[i] = r;
  }
}

// ---------------------------------------------------------------------------
// P6: C[M,N] = A[M,K] * B[N,K]^T + bias  (bf16 in, f32 out)
// 256 thr / 4 waves (2x2 of 64x64), 128x128 tile, BK=64, XOR-swizzled LDS.
// Explicit 2-slot double-buffer with COUNTED vmcnt (T3/T4 minimum).
// VALIDATED R2: 90 -> 76 us, MfmaUtil 31 -> 39.5%, conflicts 0.  ~904 TF
// = the known ~900 TF ceiling of the 128^2 2-barrier structure; 8-phase
// 256^2 maps badly (128 WGs on 256 CUs at M=2048).  Do not touch.
// ---------------------------------------------------------------------------
#define BK 64
#define NT (IN_N / BK)

__device__ __forceinline__ void gload_lds16(const void* gp, void* lp) {
  typedef const __attribute__((address_space(1))) void* gptr_t;
  typedef __attribute__((address_space(3))) void* lptr_t;
  __builtin_amdgcn_global_load_lds((gptr_t)(unsigned long long)gp,
                                   (lptr_t)(unsigned int)(unsigned long long)lp,
                                   16, 0, 0);
}

// stage one 128x64 A-tile + B-tile into slot LDS (8 gloads/thread = 8 vmcnt
// ticks/wave; all waves issue uniformly so vmcnt bookkeeping is wave-uniform)
__device__ __forceinline__ void stage_tile(const unsigned short* __restrict__ A,
                                           const unsigned short* __restrict__ B,
                                           unsigned short* as, unsigned short* bs,
                                           int gm0, int gn0, int kt,
                                           int r0, int srow, int schunk) {
#pragma unroll
  for (int j = 0; j < 4; ++j) {
    gload_lds16(A + ((size_t)(gm0 + r0 + j * 8 + srow) * IN_N + kt + schunk * 8),
                as + (size_t)(r0 + j * 8) * BK);
    gload_lds16(B + ((size_t)(gn0 + r0 + j * 8 + srow) * IN_N + kt + schunk * 8),
                bs + (size_t)(r0 + j * 8) * BK);
  }
}

__global__ __launch_bounds__(256) void gemm_bt_bias(const unsigned short* __restrict__ A,
                                                    const unsigned short* __restrict__ B,
                                                    const float* __restrict__ bias,
                                                    float* __restrict__ C) {
  __shared__ __align__(16) unsigned short As[2][128 * BK];   // 2 x 16 KB
  __shared__ __align__(16) unsigned short Bs[2][128 * BK];   // 2 x 16 KB
  const int tid  = threadIdx.x;
  const int wave = tid >> 6;
  const int lane = tid & 63;
  const int gm0 = blockIdx.y * 128;
  const int gn0 = blockIdx.x * 128;

  f32x4 acc[4][4] = {};
  const int wm = wave >> 1, wn = wave & 1;     // 2x2 waves, 64x64 each
  // staging map: dest row r0+ (lane>>3), dest chunk lane&7 gets src chunk ^row
  const int srow   = lane >> 3;                // 0..7
  const int schunk = (lane & 7) ^ srow;        // XOR swizzle
  const int r0     = wave * 32;                // per-wave staging row base
  // fragment map
  const int l7 = lane & 7;
  const int qbase = lane >> 4;                 // 0..3
  const int fra = wm * 64 + (lane & 15);
  const int frb = wn * 64 + (lane & 15);

  // prologue: fill both slots
  stage_tile(A, B, As[0], Bs[0], gm0, gn0, 0,  r0, srow, schunk);
  stage_tile(A, B, As[1], Bs[1], gm0, gn0, BK, r0, srow, schunk);

  for (int t = 0; t < NT; ++t) {
    const int S = t & 1;
    // tile t landed (everything except the newest 8 loads = tile t+1);
    // last iter has nothing in flight behind it -> drain.
    if (t < NT - 1) asm volatile("s_waitcnt vmcnt(8)" ::: "memory");
    else            asm volatile("s_waitcnt vmcnt(0)" ::: "memory");
    __builtin_amdgcn_sched_barrier(0);   // rule #18: pin code motion at the wait
    __builtin_amdgcn_s_barrier();        // raw barrier: no implicit vmcnt(0) drain
    __builtin_amdgcn_sched_barrier(0);

#pragma unroll
    for (int kk = 0; kk < 2; ++kk) {
      bf16x8 af[4], bfr[4];
      const int q = kk * 4 + qbase;            // logical 16B chunk 0..7
#pragma unroll
      for (int i = 0; i < 4; ++i) {
        af[i]  = *(const bf16x8*)&As[S][(fra + i * 16) * BK + ((q ^ l7) * 8)];
        bfr[i] = *(const bf16x8*)&Bs[S][(frb + i * 16) * BK + ((q ^ l7) * 8)];
      }
#pragma unroll
      for (int mi = 0; mi < 4; ++mi)
#pragma unroll
        for (int ni = 0; ni < 4; ++ni)
          acc[mi][ni] = __builtin_amdgcn_mfma_f32_16x16x32_bf16(af[mi], bfr[ni], acc[mi][ni], 0, 0, 0);
    }
    __builtin_amdgcn_sched_barrier(0);
    __builtin_amdgcn_s_barrier();   // all waves done reading slot S
    if (t + 2 < NT)                 // refill the slot just freed
      stage_tile(A, B, As[S], Bs[S], gm0, gn0, (t + 2) * BK, r0, srow, schunk);
  }

  // epilogue: C/D layout col = lane&15, row = (lane>>4)*4 + r   [m89/m91]
  const int col0 = gn0 + wn * 64 + (lane & 15);
  const int row0 = gm0 + wm * 64 + (lane >> 4) * 4;
#pragma unroll
  for (int mi = 0; mi < 4; ++mi) {
#pragma unroll
    for (int ni = 0; ni < 4; ++ni) {
      int col = col0 + ni * 16;
      float bv = bias[col];
#pragma unroll
      for (int r = 0; r < 4; ++r) {
        int row = row0 + mi * 16 + r;
        C[(size_t)row * OUT_N + col] = acc[mi][ni][r] + bv;
      }
    }
  }
}

// ---------------------------------------------------------------------------
extern "C" void kernel_launch(void* const* d_in, const int* in_sizes, int n_in,
                              void* d_out, int out_size, void* d_ws, size_t ws_size,
                              hipStream_t stream) {
  const float* data = (const float*)d_in[0];
  const float* wr   = (const float*)d_in[1];
  const float* wi   = (const float*)d_in[2];
  const float* bias = (const float*)d_in[3];
  const int*   zmat = (const int*)d_in[4];

  char* ws = (char*)d_ws;
  float2* wt = (float2*)ws;                                  // 2049*4096*8
  float2* y  = (float2*)(ws + 67141632ull);                  // 4096*2049*8
  unsigned short* wbf = (unsigned short*)ws;                 // 4096*4096*2 (over dead wt)
  unsigned short* dbf = (unsigned short*)(ws + 33554432ull); // 2048*4096*2

  hipLaunchKernelGGL(mask_transpose, dim3(33, 128), dim3(32, 8), 0, stream, wr, wi, zmat, wt);
  hipLaunchKernelGGL(col_ifft,       dim3(2049),    dim3(256),   0, stream, wt);
  hipLaunchKernelGGL(transpose_ko,   dim3(65, 128), dim3(32, 8), 0, stream, wt, y);
  hipLaunchKernelGGL(row_irfft2,     dim3(2048),    dim3(256),   0, stream, y, wbf);
  hipLaunchKernelGGL(cvt_bf16,       dim3(8192),    dim3(256),   0, stream, data, dbf, (BATCH * IN_N) / 4);
  hipLaunchKernelGGL(gemm_bt_bias,   dim3(OUT_N / 128, BATCH / 128), dim3(256), 0, stream,
                     dbf, wbf, bias, (float*)d_out);
}

// Round 4
// 328.720 us; speedup vs baseline: 1.2266x; 1.0784x over previous
//
#include <hip/hip_runtime.h>
#include <hip/hip_bf16.h>
#include <stdint.h>

#define OUT_N 4096
#define IN_N  4096
#define BATCH 2048
#define KHALF 2049   // IN/2 + 1

typedef __bf16 bf16x8 __attribute__((ext_vector_type(8)));
typedef float  f32x4  __attribute__((ext_vector_type(4)));

__device__ __forceinline__ unsigned short f2bf(float f) {
  unsigned int u = __builtin_bit_cast(unsigned int, f);
  u += 0x7FFFu + ((u >> 16) & 1u);   // round-to-nearest-even
  return (unsigned short)(u >> 16);
}

// ---------------------------------------------------------------------------
// complex helpers
// ---------------------------------------------------------------------------
__device__ __forceinline__ float2 cmul(float2 a, float2 b) {
  return make_float2(a.x * b.x - a.y * b.y, a.x * b.y + a.y * b.x);
}
__device__ __forceinline__ float2 cadd(float2 a, float2 b) { return make_float2(a.x + b.x, a.y + b.y); }
__device__ __forceinline__ float2 csub(float2 a, float2 b) { return make_float2(a.x - b.x, a.y - b.y); }
__device__ __forceinline__ float2 muli(float2 a) { return make_float2(-a.y, a.x); }  // *e^{+i pi/2}

// inverse DFT4 (w = +i)
__device__ __forceinline__ void dft4i(float2& x0, float2& x1, float2& x2, float2& x3) {
  float2 t0 = cadd(x0, x2), t1 = csub(x0, x2);
  float2 t2 = cadd(x1, x3), t3 = csub(x1, x3);
  float2 it3 = muli(t3);
  x0 = cadd(t0, t2); x2 = csub(t0, t2);
  x1 = cadd(t1, it3); x3 = csub(t1, it3);
}

#define C8f  0.70710678118654752f
#define C16f 0.92387953251128676f
#define S16f 0.38268343236508977f

// inverse DFT16 in registers
__device__ __forceinline__ void dft16i(float2 r[16]) {
  float2 t[16];
#pragma unroll
  for (int b = 0; b < 4; ++b) {
    float2 a0 = r[b], a1 = r[4 + b], a2 = r[8 + b], a3 = r[12 + b];
    dft4i(a0, a1, a2, a3);
    t[b * 4 + 0] = a0; t[b * 4 + 1] = a1; t[b * 4 + 2] = a2; t[b * 4 + 3] = a3;
  }
  const float2 W1 = make_float2(C16f, S16f);
  const float2 W2 = make_float2(C8f, C8f);
  const float2 W3 = make_float2(S16f, C16f);
  const float2 W6 = make_float2(-C8f, C8f);
  const float2 W9 = make_float2(-C16f, -S16f);
  t[5]  = cmul(t[5],  W1);  t[6]  = cmul(t[6],  W2);  t[7]  = cmul(t[7],  W3);
  t[9]  = cmul(t[9],  W2);  t[10] = muli(t[10]);      t[11] = cmul(t[11], W6);
  t[13] = cmul(t[13], W3);  t[14] = cmul(t[14], W6);  t[15] = cmul(t[15], W9);
#pragma unroll
  for (int q = 0; q < 4; ++q) {
    float2 a0 = t[q], a1 = t[4 + q], a2 = t[8 + q], a3 = t[12 + q];
    dft4i(a0, a1, a2, a3);
    r[q] = a0; r[q + 4] = a1; r[q + 8] = a2; r[q + 12] = a3;
  }
}

// apply r[k] *= e^{i k theta} for k=1..15 via recurrence
__device__ __forceinline__ void twiddle16(float2 r[16], float theta) {
  float sn, cs;
  __sincosf(theta, &sn, &cs);
  float2 w = make_float2(cs, sn);
  float2 wk = w;
  r[1] = cmul(r[1], wk);
#pragma unroll
  for (int k = 2; k < 16; ++k) {
    wk = cmul(wk, w);
    r[k] = cmul(r[k], wk);
  }
}

// ---------------------------------------------------------------------------
// 4096-pt inverse FFT (unnormalized, e^{+i}), radix 16^3 in registers.
// Entry: thread t holds r[n1] = x[256*n1 + t].  Exit: r[d] = X[t + 256*d].
// LDS workspace: EXACTLY 4096 float2 (32 KB).  Bank spread via per-row XOR
// swizzle: slot (row k1, col j) -> k1*256 + (j ^ k1); bijective per row, and
// every access phase lands exactly 4 lanes per bank-pair (= wave64-b64
// floor, same distribution as a padded pitch-257/273 scheme).
// Caller must sync before calling if lds fed r.
// ---------------------------------------------------------------------------
__device__ void fft4096_core(float2 r[16], float2* lds, int t) {
  dft16i(r);
  twiddle16(r, 1.53398078788564123e-3f * (float)t);   // 2*pi/4096 * t
#pragma unroll
  for (int k1 = 0; k1 < 16; ++k1) lds[k1 * 256 + (t ^ k1)] = r[k1];
  __syncthreads();
  const int k1 = t & 15, b = t >> 4;
  float2 s[16];
#pragma unroll
  for (int a = 0; a < 16; ++a) s[a] = lds[k1 * 256 + ((16 * a + b) ^ k1)];
  __syncthreads();
  dft16i(s);
  twiddle16(s, 2.45436926061702596e-2f * (float)b);   // 2*pi/256 * b
#pragma unroll
  for (int c = 0; c < 16; ++c) lds[k1 * 256 + ((c * 16 + b) ^ k1)] = s[c];
  __syncthreads();
#pragma unroll
  for (int bb = 0; bb < 16; ++bb) r[bb] = lds[k1 * 256 + ((b * 16 + bb) ^ k1)];
  dft16i(r);
}

// ---------------------------------------------------------------------------
// P1: mask + transpose. W[o][k] (k<2049) -> WT[k][o] (complex float2)
// 64(k) x 32(o) tiles, float2/int2 loads. blockIdx.x==32 handles k=2048.
// ---------------------------------------------------------------------------
__global__ void mask_transpose(const float* __restrict__ wr, const float* __restrict__ wi,
                               const int* __restrict__ zmat, float2* __restrict__ wt) {
  __shared__ float2 tile[32][65];   // [o-local][k-local], pitch 65 -> 2-way (free)
  const int tx = threadIdx.x;       // 0..31
  const int ty = threadIdx.y;       // 0..7
  const int o0 = blockIdx.y * 32;
  if (blockIdx.x == 32) {           // Nyquist column k = 2048
    int t = ty * 32 + tx;
    if (t < 32) {
      int o = o0 + t;
      size_t idx = (size_t)o * IN_N + 2048;
      float2 v = make_float2(0.f, 0.f);
      if (zmat[idx] <= 8388608) v = make_float2(wr[idx], wi[idx]);
      wt[(size_t)2048 * OUT_N + o] = v;
    }
    return;
  }
  const int k0 = blockIdx.x * 64;
#pragma unroll
  for (int r = 0; r < 4; ++r) {
    int o = o0 + ty + r * 8;
    size_t base = (size_t)o * IN_N + k0 + tx * 2;
    float2 vr = *(const float2*)&wr[base];
    float2 vi = *(const float2*)&wi[base];
    int2   z  = *(const int2*)&zmat[base];
    tile[ty + r * 8][tx * 2]     = (z.x <= 8388608) ? make_float2(vr.x, vi.x) : make_float2(0.f, 0.f);
    tile[ty + r * 8][tx * 2 + 1] = (z.y <= 8388608) ? make_float2(vr.y, vi.y) : make_float2(0.f, 0.f);
  }
  __syncthreads();
#pragma unroll
  for (int rr = 0; rr < 8; ++rr) {
    int k = k0 + ty + rr * 8;
    int o = o0 + tx;
    wt[(size_t)k * OUT_N + o] = tile[tx][ty + rr * 8];
  }
}

// ---------------------------------------------------------------------------
// P2: per-row inverse FFT of WT, in place, UNnormalized (1/4096^2 in P4)
// No min-waves clause (R2's (256,5) cap regressed ~50 us — spill suspect).
// ---------------------------------------------------------------------------
__global__ __launch_bounds__(256) void col_ifft(float2* __restrict__ wt) {
  __shared__ float2 lds[4096];
  const int t = threadIdx.x;
  float2* row = wt + (size_t)blockIdx.x * OUT_N;
  float2 r[16];
#pragma unroll
  for (int n1 = 0; n1 < 16; ++n1) r[n1] = row[n1 * 256 + t];
  fft4096_core(r, lds, t);
#pragma unroll
  for (int d = 0; d < 16; ++d) row[t + 256 * d] = r[d];
}

// ---------------------------------------------------------------------------
// P4': TWO rows per block, reading WT[k][o] DIRECTLY (P3 transpose deleted).
// Rows oa=2L, ob=2L+1 are adjacent in o -> one float4 load per k fetches
// both rows' element k: wt4[k*2048 + L].  Per-lane reads are 32KB-strided
// (16B/128B line), but each line covers 16 o = 8 consecutive L-blocks;
// the XCD-chunked swizzle lb=(bid&7)*256+(bid>>3) (bijective, 2048%8==0)
// puts those 8 blocks on ONE XCD so the line is fetched into that L2 once
// and served 8x at L2 speed.  Unique HBM traffic for wt unchanged (67 MB,
// L3-resident); saves P3's 134 MB + y's 67 MB read entirely.
// ifft(Ya_ext + i*Yb_ext) = a + i*b exactly; scale 1/4096^2 covers P2 too.
// LDS: float4 lsf[2048] = 32 KB holds k=0..2047 of BOTH rows; Nyquist
// k=2048 read straight from global by the one lane (n1==8,t==0) needing it.
// ---------------------------------------------------------------------------
__global__ __launch_bounds__(256) void row_irfft2(const float2* __restrict__ wt,
                                                  unsigned short* __restrict__ wbf) {
  __shared__ float4 lsf[2048];      // lsf[k] = {Ya.re, Ya.im, Yb.re, Yb.im}
  const int t = threadIdx.x;
  const int bid = (int)blockIdx.x;
  const int lb  = (bid & 7) * 256 + (bid >> 3);   // XCD-chunked logical block
  const int oa = lb * 2, ob = oa + 1;
  const float4* wt4 = (const float4*)wt;          // wt4[k*2048 + oa/2]
  const int oq = oa >> 1;
#pragma unroll
  for (int j = 0; j < 8; ++j) {
    int k = t + j * 256;            // 0..2047
    lsf[k] = wt4[(size_t)k * 2048 + oq];
  }
  __syncthreads();
  float2 r[16];
#pragma unroll
  for (int n1 = 0; n1 < 16; ++n1) {
    int m = n1 * 256 + t;
    float2 za, zb;
    if (m == 0)        { float4 v = lsf[0];    za = make_float2(v.x, 0.f); zb = make_float2(v.z, 0.f); }
    else if (m < 2048) { float4 v = lsf[m];    za = make_float2(v.x, v.y); zb = make_float2(v.z, v.w); }
    else if (m == 2048){ float4 v = wt4[(size_t)2048 * 2048 + oq];   // Nyquist, single lane
                         za = make_float2(v.x, 0.f); zb = make_float2(v.z, 0.f); }
    else { float4 v = lsf[4096 - m];
           za = make_float2(v.x, -v.y); zb = make_float2(v.z, -v.w); }
    r[n1] = make_float2(za.x - zb.y, za.y + zb.x);   // za + i*zb
  }
  __syncthreads();
  fft4096_core(r, (float2*)lsf, t);
  const float sc = 1.0f / (4096.0f * 4096.0f);
  unsigned short* orow_a = wbf + (size_t)oa * IN_N;
  unsigned short* orow_b = wbf + (size_t)ob * IN_N;
#pragma unroll
  for (int d = 0; d < 16; ++d) {
    orow_a[t + 256 * d] = f2bf(r[d].x * sc);
    orow_b[t + 256 * d] = f2bf(r[d].y * sc);
  }
}

// ---------------------------------------------------------------------------
// P5: data f32 -> bf16
// ---------------------------------------------------------------------------
__global__ void cvt_bf16(const float* __restrict__ x, unsigned short* __restrict__ o, int n4) {
  int i = blockIdx.x * blockDim.x + threadIdx.x;
  if (i < n4) {
    float4 v = ((const float4*)x)[i];
    ushort4 r;
    r.x = f2bf(v.x); r.y = f2bf(v.y); r.z = f2bf(v.z); r.w = f2bf(v.w);
    ((ushort4*)o)[i] = r;
  }
}

// ---------------------------------------------------------------------------
// P6: C[M,N] = A[M,K] * B[N,K]^T + bias  (bf16 in, f32 out)
// 256 thr / 4 waves (2x2 of 64x64), 128x128 tile, BK=64, XOR-swizzled LDS.
// Explicit 2-slot double-buffer with COUNTED vmcnt (T3/T4 minimum).
// VALIDATED R2/R3: 90 -> 76 us, MfmaUtil 31 -> ~39%, conflicts 0.  ~904 TF
// = the known ~900 TF ceiling of the 128^2 2-barrier structure; 8-phase
// 256^2 maps badly (128 WGs on 256 CUs at M=2048).  Do not touch.
// ---------------------------------------------------------------------------
#define BK 64
#define NT (IN_N / BK)

__device__ __forceinline__ void gload_lds16(const void* gp, void* lp) {
  typedef const __attribute__((address_space(1))) void* gptr_t;
  typedef __attribute__((address_space(3))) void* lptr_t;
  __builtin_amdgcn_global_load_lds((gptr_t)(unsigned long long)gp,
                                   (lptr_t)(unsigned int)(unsigned long long)lp,
                                   16, 0, 0);
}

// stage one 128x64 A-tile + B-tile into slot LDS (8 gloads/thread = 8 vmcnt
// ticks/wave; all waves issue uniformly so vmcnt bookkeeping is wave-uniform)
__device__ __forceinline__ void stage_tile(const unsigned short* __restrict__ A,
                                           const unsigned short* __restrict__ B,
                                           unsigned short* as, unsigned short* bs,
                                           int gm0, int gn0, int kt,
                                           int r0, int srow, int schunk) {
#pragma unroll
  for (int j = 0; j < 4; ++j) {
    gload_lds16(A + ((size_t)(gm0 + r0 + j * 8 + srow) * IN_N + kt + schunk * 8),
                as + (size_t)(r0 + j * 8) * BK);
    gload_lds16(B + ((size_t)(gn0 + r0 + j * 8 + srow) * IN_N + kt + schunk * 8),
                bs + (size_t)(r0 + j * 8) * BK);
  }
}

__global__ __launch_bounds__(256) void gemm_bt_bias(const unsigned short* __restrict__ A,
                                                    const unsigned short* __restrict__ B,
                                                    const float* __restrict__ bias,
                                                    float* __restrict__ C) {
  __shared__ __align__(16) unsigned short As[2][128 * BK];   // 2 x 16 KB
  __shared__ __align__(16) unsigned short Bs[2][128 * BK];   // 2 x 16 KB
  const int tid  = threadIdx.x;
  const int wave = tid >> 6;
  const int lane = tid & 63;
  const int gm0 = blockIdx.y * 128;
  const int gn0 = blockIdx.x * 128;

  f32x4 acc[4][4] = {};
  const int wm = wave >> 1, wn = wave & 1;     // 2x2 waves, 64x64 each
  // staging map: dest row r0+ (lane>>3), dest chunk lane&7 gets src chunk ^row
  const int srow   = lane >> 3;                // 0..7
  const int schunk = (lane & 7) ^ srow;        // XOR swizzle
  const int r0     = wave * 32;                // per-wave staging row base
  // fragment map
  const int l7 = lane & 7;
  const int qbase = lane >> 4;                 // 0..3
  const int fra = wm * 64 + (lane & 15);
  const int frb = wn * 64 + (lane & 15);

  // prologue: fill both slots
  stage_tile(A, B, As[0], Bs[0], gm0, gn0, 0,  r0, srow, schunk);
  stage_tile(A, B, As[1], Bs[1], gm0, gn0, BK, r0, srow, schunk);

  for (int t = 0; t < NT; ++t) {
    const int S = t & 1;
    // tile t landed (everything except the newest 8 loads = tile t+1);
    // last iter has nothing in flight behind it -> drain.
    if (t < NT - 1) asm volatile("s_waitcnt vmcnt(8)" ::: "memory");
    else            asm volatile("s_waitcnt vmcnt(0)" ::: "memory");
    __builtin_amdgcn_sched_barrier(0);   // rule #18: pin code motion at the wait
    __builtin_amdgcn_s_barrier();        // raw barrier: no implicit vmcnt(0) drain
    __builtin_amdgcn_sched_barrier(0);

#pragma unroll
    for (int kk = 0; kk < 2; ++kk) {
      bf16x8 af[4], bfr[4];
      const int q = kk * 4 + qbase;            // logical 16B chunk 0..7
#pragma unroll
      for (int i = 0; i < 4; ++i) {
        af[i]  = *(const bf16x8*)&As[S][(fra + i * 16) * BK + ((q ^ l7) * 8)];
        bfr[i] = *(const bf16x8*)&Bs[S][(frb + i * 16) * BK + ((q ^ l7) * 8)];
      }
#pragma unroll
      for (int mi = 0; mi < 4; ++mi)
#pragma unroll
        for (int ni = 0; ni < 4; ++ni)
          acc[mi][ni] = __builtin_amdgcn_mfma_f32_16x16x32_bf16(af[mi], bfr[ni], acc[mi][ni], 0, 0, 0);
    }
    __builtin_amdgcn_sched_barrier(0);
    __builtin_amdgcn_s_barrier();   // all waves done reading slot S
    if (t + 2 < NT)                 // refill the slot just freed
      stage_tile(A, B, As[S], Bs[S], gm0, gn0, (t + 2) * BK, r0, srow, schunk);
  }

  // epilogue: C/D layout col = lane&15, row = (lane>>4)*4 + r   [m89/m91]
  const int col0 = gn0 + wn * 64 + (lane & 15);
  const int row0 = gm0 + wm * 64 + (lane >> 4) * 4;
#pragma unroll
  for (int mi = 0; mi < 4; ++mi) {
#pragma unroll
    for (int ni = 0; ni < 4; ++ni) {
      int col = col0 + ni * 16;
      float bv = bias[col];
#pragma unroll
      for (int r = 0; r < 4; ++r) {
        int row = row0 + mi * 16 + r;
        C[(size_t)row * OUT_N + col] = acc[mi][ni][r] + bv;
      }
    }
  }
}

// ---------------------------------------------------------------------------
// Workspace layout (wt now stays LIVE through P4' -> wbf must not overlay it):
//   wt  [0,          67,141,632)   2049*4096*8  (float2)
//   wbf [67,141,632, 100,696,064)  4096*4096*2  (bf16)   -- former y region
//   dbf [100,696,064, 117,473,280) 2048*4096*2  (bf16)
// Max usage 117.5 MB < previous 134.3 MB -> fits existing ws.
// ---------------------------------------------------------------------------
extern "C" void kernel_launch(void* const* d_in, const int* in_sizes, int n_in,
                              void* d_out, int out_size, void* d_ws, size_t ws_size,
                              hipStream_t stream) {
  const float* data = (const float*)d_in[0];
  const float* wr   = (const float*)d_in[1];
  const float* wi   = (const float*)d_in[2];
  const float* bias = (const float*)d_in[3];
  const int*   zmat = (const int*)d_in[4];

  char* ws = (char*)d_ws;
  float2* wt = (float2*)ws;                                   // 2049*4096*8
  unsigned short* wbf = (unsigned short*)(ws + 67141632ull);  // 4096*4096*2
  unsigned short* dbf = (unsigned short*)(ws + 100696064ull); // 2048*4096*2

  hipLaunchKernelGGL(mask_transpose, dim3(33, 128), dim3(32, 8), 0, stream, wr, wi, zmat, wt);
  hipLaunchKernelGGL(col_ifft,       dim3(2049),    dim3(256),   0, stream, wt);
  hipLaunchKernelGGL(row_irfft2,     dim3(2048),    dim3(256),   0, stream, wt, wbf);
  hipLaunchKernelGGL(cvt_bf16,       dim3(8192),    dim3(256),   0, stream, data, dbf, (BATCH * IN_N) / 4);
  hipLaunchKernelGGL(gemm_bt_bias,   dim3(OUT_N / 128, BATCH / 128), dim3(256), 0, stream,
                     dbf, wbf, bias, (float*)d_out);
}